// Round 8
// baseline (458.784 us; speedup 1.0000x reference)
//
#include <hip/hip_runtime.h>
#include <math.h>

// MultiHeadAttention: B=2, S=2048, D=2048, H=16, dh=128, causal.
// v11: gemm_qkv reverted to the v5 runtime-cur loop (135.8us measured) --
// the v10 x2-unroll regressed (+10us). Rope fusion kept but via angle
// recurrence (3 sincos + 31 complex rotations per j, q-scale folded in).
// Attn: softmax via exp2f (log2e folded into q-scale at rope time);
// P stride 80->84 kills the 4-way quad-row bank conflict (4*40==0 mod 32).
// gemm_out = v9 btn128. Casts/transpose unchanged.

typedef _Float16 half8 __attribute__((ext_vector_type(8)));
typedef _Float16 half4v __attribute__((ext_vector_type(4)));
typedef float f32x4 __attribute__((ext_vector_type(4)));

__device__ __forceinline__ void gl_lds16(const void* g, void* l) {
  __builtin_amdgcn_global_load_lds(
      (const __attribute__((address_space(1))) unsigned int*)g,
      (__attribute__((address_space(3))) unsigned int*)l, 16, 0, 0);
}

// ---------------- cast fp32 -> fp16 ----------------
__global__ void cast_f32_f16(const float* __restrict__ src, _Float16* __restrict__ dst, int n4) {
  int i = blockIdx.x * blockDim.x + threadIdx.x;
  if (i >= n4) return;
  float4 v = reinterpret_cast<const float4*>(src)[i];
  half4v o;
  o[0] = (_Float16)v.x; o[1] = (_Float16)v.y; o[2] = (_Float16)v.z; o[3] = (_Float16)v.w;
  reinterpret_cast<half4v*>(dst)[i] = o;
}

__global__ void cast_w(const float* __restrict__ w0, const float* __restrict__ w1,
                       const float* __restrict__ w2, const float* __restrict__ w3,
                       _Float16* __restrict__ wdst) {
  const float* s = blockIdx.y == 0 ? w0 : blockIdx.y == 1 ? w1 : blockIdx.y == 2 ? w2 : w3;
  int i = blockIdx.x * blockDim.x + threadIdx.x;  // < 1048576 float4 groups
  float4 v = reinterpret_cast<const float4*>(s)[i];
  half4v o;
  o[0] = (_Float16)v.x; o[1] = (_Float16)v.y; o[2] = (_Float16)v.z; o[3] = (_Float16)v.w;
  reinterpret_cast<half4v*>(wdst)[(size_t)blockIdx.y * 1048576 + i] = o;
}

// ---------------- QKV GEMM 256x256 (v5 loop) + fused bias/rope/scale ----------------
// q is additionally scaled by (1/sqrt(128))*log2(e) so attn can use exp2.
__global__ __launch_bounds__(512, 2) void gemm_qkv(
    const _Float16* __restrict__ A,   // M x K
    const _Float16* __restrict__ B,   // N x K (wq|wk|wv)
    const float* __restrict__ b0, const float* __restrict__ b1,
    const float* __restrict__ b2,
    _Float16* __restrict__ Cout,      // M x N
    int M, int N, int K) {
  __shared__ _Float16 As[2][16384];  // 64 KB
  __shared__ _Float16 Bs[2][16384];  // 64 KB (sigma-permuted rows)
  const int bm = blockIdx.y * 256, bn = blockIdx.x * 256;
  const int tid = threadIdx.x;
  const int wave = tid >> 6, lane = tid & 63;
  const int quad = lane >> 4, l16 = lane & 15;
  const int wm = (wave >> 2) * 128, wn = (wave & 3) * 64;

  const int srow = tid >> 3;
  const int sx = (tid & 7) ^ (srow & 7);
  const _Float16* Ag = A + (size_t)(bm + srow) * K + sx * 8;
  const _Float16* Bg[4];
#pragma unroll
  for (int c = 0; c < 4; ++c) {
    int r = (((c * 2 + (srow >> 5)) & 3) << 6) + ((c >> 1) << 5) + (srow & 31);
    Bg[c] = B + (size_t)(bn + r) * K + sx * 8;
  }

#define STAGE_A(buf, R, kt) \
  gl_lds16(Ag + (size_t)(R) * K + (kt) * 64, &As[buf][(R) * 64 + tid * 8])
#define STAGE_B(buf, c, kt) \
  gl_lds16(Bg[c] + (kt) * 64, &Bs[buf][(c) * 4096 + tid * 8])

  const int axor = l16 & 7;
  const int sl0 = ((0 + quad) ^ axor) * 8;
  const int sl1 = ((4 + quad) ^ axor) * 8;
  const int aoff = (wm + l16) * 64;
  const int q4 = (wn >> 6) * 32;

#define RD_A(i, kk) \
  (*reinterpret_cast<const half8*>(&As[cur][aoff + (i) * 1024 + ((kk) ? sl1 : sl0)]))
#define RD_B(j, kk) \
  (*reinterpret_cast<const half8*>( \
      &Bs[cur][((((j) >> 1) * 128 + q4 + ((j) & 1) * 16 + l16)) * 64 + ((kk) ? sl1 : sl0)]))

  f32x4 acc[8][4];
#pragma unroll
  for (int i = 0; i < 8; ++i)
#pragma unroll
    for (int j = 0; j < 4; ++j) acc[i][j] = f32x4{0.f, 0.f, 0.f, 0.f};

  half8 a[4][2], b[4][2];
  const int NT = K >> 6;

  STAGE_A(0, 0, 0); STAGE_A(0, 128, 0);
  STAGE_B(0, 0, 0); STAGE_B(0, 1, 0);
  STAGE_B(0, 2, 0); STAGE_B(0, 3, 0);
  STAGE_A(0, 64, 0); STAGE_A(0, 192, 0);
  if (NT > 1) {
    STAGE_A(1, 0, 1); STAGE_A(1, 128, 1);
    STAGE_B(1, 0, 1); STAGE_B(1, 1, 1);
    STAGE_B(1, 2, 1); STAGE_B(1, 3, 1);
    asm volatile("s_waitcnt vmcnt(6)");
  } else {
    asm volatile("s_waitcnt vmcnt(0)");
  }
  __builtin_amdgcn_s_barrier();

  for (int t = 0; t < NT; ++t) {
    const int cur = t & 1, nxt = cur ^ 1;
    const bool pf1 = (t + 1 < NT);
    const bool pf2 = (t + 2 < NT);

    // ---- P1 ----
#pragma unroll
    for (int i = 0; i < 4; ++i) {
      a[i][0] = RD_A(i, 0); a[i][1] = RD_A(i, 1);
    }
#pragma unroll
    for (int j = 0; j < 2; ++j) {
      b[j][0] = RD_B(j, 0); b[j][1] = RD_B(j, 1);
    }
    if (pf1) { STAGE_A(nxt, 64, t + 1); STAGE_A(nxt, 192, t + 1); }
    __builtin_amdgcn_s_barrier();
    __builtin_amdgcn_s_setprio(1);
#pragma unroll
    for (int i = 0; i < 4; ++i)
#pragma unroll
      for (int j = 0; j < 2; ++j) {
        acc[i][j] = __builtin_amdgcn_mfma_f32_16x16x32_f16(a[i][0], b[j][0], acc[i][j], 0, 0, 0);
        acc[i][j] = __builtin_amdgcn_mfma_f32_16x16x32_f16(a[i][1], b[j][1], acc[i][j], 0, 0, 0);
      }
    __builtin_amdgcn_s_setprio(0);
    __builtin_amdgcn_s_barrier();

    // ---- P2 ----
#pragma unroll
    for (int j = 2; j < 4; ++j) {
      b[j][0] = RD_B(j, 0); b[j][1] = RD_B(j, 1);
    }
    if (pf2) { STAGE_A(cur, 0, t + 2); STAGE_A(cur, 128, t + 2); }
    __builtin_amdgcn_s_barrier();
    __builtin_amdgcn_s_setprio(1);
#pragma unroll
    for (int i = 0; i < 4; ++i)
#pragma unroll
      for (int j = 2; j < 4; ++j) {
        acc[i][j] = __builtin_amdgcn_mfma_f32_16x16x32_f16(a[i][0], b[j][0], acc[i][j], 0, 0, 0);
        acc[i][j] = __builtin_amdgcn_mfma_f32_16x16x32_f16(a[i][1], b[j][1], acc[i][j], 0, 0, 0);
      }
    __builtin_amdgcn_s_setprio(0);
    __builtin_amdgcn_s_barrier();

    // ---- P3 ----
#pragma unroll
    for (int i = 0; i < 4; ++i) {
      a[i][0] = RD_A(i + 4, 0); a[i][1] = RD_A(i + 4, 1);
    }
    if (pf2) { STAGE_B(cur, 0, t + 2); STAGE_B(cur, 1, t + 2); }
    __builtin_amdgcn_s_barrier();
    __builtin_amdgcn_s_setprio(1);
#pragma unroll
    for (int i = 0; i < 4; ++i)
#pragma unroll
      for (int j = 0; j < 2; ++j) {
        acc[i + 4][j] = __builtin_amdgcn_mfma_f32_16x16x32_f16(a[i][0], b[j][0], acc[i + 4][j], 0, 0, 0);
        acc[i + 4][j] = __builtin_amdgcn_mfma_f32_16x16x32_f16(a[i][1], b[j][1], acc[i + 4][j], 0, 0, 0);
      }
    __builtin_amdgcn_s_setprio(0);
    __builtin_amdgcn_s_barrier();

    // ---- P4 ----
    if (pf2) { STAGE_B(cur, 2, t + 2); STAGE_B(cur, 3, t + 2); }
    __builtin_amdgcn_s_barrier();
    __builtin_amdgcn_s_setprio(1);
#pragma unroll
    for (int i = 0; i < 4; ++i)
#pragma unroll
      for (int j = 2; j < 4; ++j) {
        acc[i + 4][j] = __builtin_amdgcn_mfma_f32_16x16x32_f16(a[i][0], b[j][0], acc[i + 4][j], 0, 0, 0);
        acc[i + 4][j] = __builtin_amdgcn_mfma_f32_16x16x32_f16(a[i][1], b[j][1], acc[i + 4][j], 0, 0, 0);
      }
    __builtin_amdgcn_s_setprio(0);
    if (pf2)
      asm volatile("s_waitcnt vmcnt(6)");
    else
      asm volatile("s_waitcnt vmcnt(0)");
    __builtin_amdgcn_s_barrier();
  }

  // ---- epilogue: bias + rope (q/k) + scale(q, incl log2e) ----
  // region = (bn+wn)>>11 wave-uniform: 0=q, 1=k, 2=v.
  const int region = (bn + wn) >> 11;
  const float qsc = 0.12754113f;  // (1/sqrt(128)) * log2(e)
#pragma unroll
  for (int j = 0; j < 4; ++j) {
    const int gc = bn + wn + j * 16 + l16;
    const float* bp = (region == 0) ? b0 : (region == 1 ? b1 : b2);
    const float bz = bp[gc & 2047];
    if (region < 2) {
      const int fi = (gc >> 1) & 63;
      const float fr = exp2f(-0.2076205059304601f * (float)fi);
      // rotation steps: +1 row and +13 rows (r=3 -> next i, r=0)
      float c1, s1, c13, s13;
      __sincosf(fr, &s1, &c1);
      __sincosf(13.0f * fr, &s13, &c13);
      const float sc = (region == 0) ? qsc : 1.0f;
      const int s0 = (bm + wm + quad * 4) & 2047;
      float cb, sb;
      __sincosf((float)s0 * fr, &sb, &cb);
      cb *= sc; sb *= sc;  // fold output scale into rotation coeffs
      const bool isodd = (gc & 1) != 0;
#pragma unroll
      for (int i = 0; i < 8; ++i) {
#pragma unroll
        for (int r = 0; r < 4; ++r) {
          const int gr = bm + wm + i * 16 + quad * 4 + r;
          float v = acc[i][j][r] + bz;
          const float p = __shfl_xor(v, 1);
          float out = isodd ? (v * cb + p * sb) : (v * cb - p * sb);
          Cout[(size_t)gr * N + gc] = (_Float16)out;
          // advance angle: +1 row (last r of last i: skip)
          if (!(i == 7 && r == 3)) {
            if (r < 3) {
              float cn = cb * c1 - sb * s1;
              sb = sb * c1 + cb * s1; cb = cn;
            } else {
              float cn = cb * c13 - sb * s13;
              sb = sb * c13 + cb * s13; cb = cn;
            }
          }
        }
      }
    } else {
#pragma unroll
      for (int i = 0; i < 8; ++i)
#pragma unroll
        for (int r = 0; r < 4; ++r) {
          const int gr = bm + wm + i * 16 + quad * 4 + r;
          Cout[(size_t)gr * N + gc] = (_Float16)(acc[i][j][r] + bz);
        }
    }
  }
#undef STAGE_A
#undef STAGE_B
#undef RD_A
#undef RD_B
}

// ---------------- output GEMM 256x128 (v9 btn128): C = A*B^T + bias, f32 ----------------
__global__ __launch_bounds__(512, 2) void gemm_out(
    const _Float16* __restrict__ A,   // M x K
    const _Float16* __restrict__ B,   // N x K
    const float* __restrict__ bias,
    float* __restrict__ Cout,         // M x N f32
    int M, int N, int K) {
  __shared__ _Float16 As[2][16384];  // 64 KB
  __shared__ _Float16 Bs[2][8192];   // 32 KB
  const int bm = blockIdx.y * 256, bn = blockIdx.x * 128;
  const int tid = threadIdx.x;
  const int wave = tid >> 6, lane = tid & 63;
  const int quad = lane >> 4, l16 = lane & 15;
  const int wm = (wave >> 2) * 128, wq = wave & 3;

  const int srow = tid >> 3;
  const int sx = (tid & 7) ^ (srow & 7);
  const _Float16* Ag = A + (size_t)(bm + srow) * K + sx * 8;
  const _Float16* Bg[2];
#pragma unroll
  for (int c = 0; c < 2; ++c)
    Bg[c] = B + (size_t)(bn + (srow >> 4) * 32 + c * 16 + (srow & 15)) * K + sx * 8;

#define STAGE_A(buf, R, kt) \
  gl_lds16(Ag + (size_t)(R) * K + (kt) * 64, &As[buf][(R) * 64 + tid * 8])
#define STAGE_B(buf, c, kt) \
  gl_lds16(Bg[c] + (kt) * 64, &Bs[buf][(c) * 4096 + tid * 8])

  const int axor = l16 & 7;
  const int sl0 = ((0 + quad) ^ axor) * 8;
  const int sl1 = ((4 + quad) ^ axor) * 8;
  const int aoff = (wm + l16) * 64;

#define RD_A(i, kk) \
  (*reinterpret_cast<const half8*>(&As[cur][aoff + (i) * 1024 + ((kk) ? sl1 : sl0)]))
#define RD_B(j, kk) \
  (*reinterpret_cast<const half8*>( \
      &Bs[cur][((j) * 64 + wq * 16 + l16) * 64 + ((kk) ? sl1 : sl0)]))

  f32x4 acc[8][2];
#pragma unroll
  for (int i = 0; i < 8; ++i)
#pragma unroll
    for (int j = 0; j < 2; ++j) acc[i][j] = f32x4{0.f, 0.f, 0.f, 0.f};

  half8 a[4][2], b[2][2];
  const int NT = K >> 6;

  STAGE_A(0, 0, 0); STAGE_A(0, 128, 0);
  STAGE_B(0, 0, 0); STAGE_B(0, 1, 0);
  STAGE_A(0, 64, 0); STAGE_A(0, 192, 0);
  if (NT > 1) {
    STAGE_A(1, 0, 1); STAGE_A(1, 128, 1);
    STAGE_B(1, 0, 1); STAGE_B(1, 1, 1);
    STAGE_A(1, 64, 1); STAGE_A(1, 192, 1);
    asm volatile("s_waitcnt vmcnt(6)");
  } else {
    asm volatile("s_waitcnt vmcnt(0)");
  }
  __builtin_amdgcn_s_barrier();

  for (int t = 0; t < NT; ++t) {
    const int cur = t & 1;
    const bool pf2 = (t + 2 < NT);

    // ---- P1 ----
#pragma unroll
    for (int i = 0; i < 4; ++i) {
      a[i][0] = RD_A(i, 0); a[i][1] = RD_A(i, 1);
    }
    b[0][0] = RD_B(0, 0); b[0][1] = RD_B(0, 1);
    __builtin_amdgcn_s_barrier();
    __builtin_amdgcn_s_setprio(1);
#pragma unroll
    for (int i = 0; i < 4; ++i) {
      acc[i][0] = __builtin_amdgcn_mfma_f32_16x16x32_f16(a[i][0], b[0][0], acc[i][0], 0, 0, 0);
      acc[i][0] = __builtin_amdgcn_mfma_f32_16x16x32_f16(a[i][1], b[0][1], acc[i][0], 0, 0, 0);
    }
    __builtin_amdgcn_s_setprio(0);
    __builtin_amdgcn_s_barrier();

    // ---- P2 ----
    b[1][0] = RD_B(1, 0); b[1][1] = RD_B(1, 1);
    if (pf2) { STAGE_A(cur, 0, t + 2); STAGE_A(cur, 128, t + 2); }
    __builtin_amdgcn_s_barrier();
    __builtin_amdgcn_s_setprio(1);
#pragma unroll
    for (int i = 0; i < 4; ++i) {
      acc[i][1] = __builtin_amdgcn_mfma_f32_16x16x32_f16(a[i][0], b[1][0], acc[i][1], 0, 0, 0);
      acc[i][1] = __builtin_amdgcn_mfma_f32_16x16x32_f16(a[i][1], b[1][1], acc[i][1], 0, 0, 0);
    }
    __builtin_amdgcn_s_setprio(0);
    __builtin_amdgcn_s_barrier();

    // ---- P3 ----
#pragma unroll
    for (int i = 0; i < 4; ++i) {
      a[i][0] = RD_A(i + 4, 0); a[i][1] = RD_A(i + 4, 1);
    }
    if (pf2) { STAGE_B(cur, 0, t + 2); STAGE_B(cur, 1, t + 2); }
    __builtin_amdgcn_s_barrier();
    __builtin_amdgcn_s_setprio(1);
#pragma unroll
    for (int i = 0; i < 4; ++i) {
      acc[i + 4][0] = __builtin_amdgcn_mfma_f32_16x16x32_f16(a[i][0], b[0][0], acc[i + 4][0], 0, 0, 0);
      acc[i + 4][0] = __builtin_amdgcn_mfma_f32_16x16x32_f16(a[i][1], b[0][1], acc[i + 4][0], 0, 0, 0);
    }
    __builtin_amdgcn_s_setprio(0);
    __builtin_amdgcn_s_barrier();

    // ---- P4 ----
    if (pf2) { STAGE_A(cur, 64, t + 2); STAGE_A(cur, 192, t + 2); }
    __builtin_amdgcn_s_barrier();
    __builtin_amdgcn_s_setprio(1);
#pragma unroll
    for (int i = 0; i < 4; ++i) {
      acc[i + 4][1] = __builtin_amdgcn_mfma_f32_16x16x32_f16(a[i][0], b[1][0], acc[i + 4][1], 0, 0, 0);
      acc[i + 4][1] = __builtin_amdgcn_mfma_f32_16x16x32_f16(a[i][1], b[1][1], acc[i + 4][1], 0, 0, 0);
    }
    __builtin_amdgcn_s_setprio(0);
    if (pf2)
      asm volatile("s_waitcnt vmcnt(6)");
    else
      asm volatile("s_waitcnt vmcnt(0)");
    __builtin_amdgcn_s_barrier();
  }

#pragma unroll
  for (int j = 0; j < 2; ++j) {
    const int gc = bn + wq * 32 + j * 16 + l16;
    const float bz = bias[gc & 2047];
#pragma unroll
    for (int i = 0; i < 8; ++i) {
#pragma unroll
      for (int r = 0; r < 4; ++r) {
        const int gr = bm + wm + i * 16 + quad * 4 + r;
        Cout[(size_t)gr * N + gc] = acc[i][j][r] + bz;
      }
    }
  }
#undef STAGE_A
#undef STAGE_B
#undef RD_A
#undef RD_B
}

// ---------------- V transpose: qkv v-cols (stride 6144) -> (B,H,dh,S) ----------------
__global__ __launch_bounds__(256) void transpose_v(const _Float16* __restrict__ qkv,
                                                   _Float16* __restrict__ vt) {
  __shared__ _Float16 t[64][72];
  const int s0 = blockIdx.x * 64;
  const int d0 = blockIdx.y * 64;
  const int bh = blockIdx.z;
  const int b = bh >> 4, h = bh & 15;
  const int tid = threadIdx.x;
#pragma unroll
  for (int p = 0; p < 2; ++p) {
    int chunk = p * 256 + tid;
    int r = chunk >> 3, c8 = (chunk & 7) * 8;
    *reinterpret_cast<half8*>(&t[r][c8]) = *reinterpret_cast<const half8*>(
        &qkv[(size_t)(b * 2048 + s0 + r) * 6144 + 4096 + h * 128 + d0 + c8]);
  }
  __syncthreads();
#pragma unroll
  for (int p = 0; p < 2; ++p) {
    int chunk = p * 256 + tid;
    int dr = chunk >> 3, c8 = (chunk & 7) * 8;
    half8 o;
#pragma unroll
    for (int j = 0; j < 8; ++j) o[j] = t[c8 + j][dr];
    *reinterpret_cast<half8*>(&vt[(size_t)(bh * 128 + d0 + dr) * 2048 + s0 + c8]) = o;
  }
}

// ---------------- Flash attention (causal), dbuf LDS K/V ----------------
// v11: softmax P = exp2(s' - 5*log2e) with s' pre-scaled by log2e at rope
// time (single v_exp_f32). P stride 84 (42 words): quad-rows land on banks
// +0/+8/+16/+24 -> conflict-free writes.
__global__ __launch_bounds__(256, 2) void attn_kernel(
    const _Float16* __restrict__ QKV,  // (4096, 6144): q|k|v
    const _Float16* __restrict__ VT,   // (32, 128, 2048)
    _Float16* __restrict__ ctx) {      // (4096, 2048)
  constexpr int LD = 6144, S = 2048;
  __shared__ _Float16 Ks[2][8192];
  __shared__ _Float16 Vs[2][8192];
  __shared__ _Float16 P[4][16][84];
  const int bid = blockIdx.x;
  const int bh = bid & 31;
  const int idx = (bid >> 5) & 7;
  const int qb = (bid >> 8) ? idx : 15 - idx;  // pairs (bid,bid+256) sum to 15
  const int b = bh >> 4, h = bh & 15;
  const int tid = threadIdx.x;
  const int wv = tid >> 6, lane = tid & 63;
  const int quad = lane >> 4, l16 = lane & 15;
  const int q0 = qb * 128 + wv * 16;   // half0 rows; half1 = q0 + 64
  const int NJ = 2 * qb + 2;           // 64-key tiles
  const float SH = 7.2134752044448169f;  // 5 * log2(e)

  const _Float16* qp0 = QKV + (size_t)(b * S + q0 + l16) * LD + h * 128;
  half8 aq0[4], aq1[4];
#pragma unroll
  for (int ks = 0; ks < 4; ++ks) {
    aq0[ks] = *reinterpret_cast<const half8*>(qp0 + ks * 32 + quad * 8);
    aq1[ks] = *reinterpret_cast<const half8*>(qp0 + (size_t)64 * LD + ks * 32 + quad * 8);
  }

  const _Float16* gk[4];
  const _Float16* gv[4];
  int lofs[4];
#pragma unroll
  for (int p = 0; p < 4; ++p) {
    int c = p * 256 + tid;
    int cs = c ^ ((c >> 3) & 7);
    int cl16 = cs & 15, cqd = (cs >> 4) & 3;
    int cks = (cs >> 6) & 3, cf = cs >> 8;
    gk[p] = QKV + (size_t)(b * S + cf * 16 + cl16) * LD + 2048 + h * 128 + cks * 32 + cqd * 8;
    int ckv = (cs >> 6) & 1, ct = cs >> 7;
    gv[p] = VT + (size_t)(bh * 128 + ct * 16 + cl16) * S + ckv * 32 + cqd * 8;
    lofs[p] = c * 8;
  }

  const int kofs = (l16 >> 3) * 64 + (((l16 & 7) ^ (quad * 2 + (l16 >> 3)))) * 8;

  f32x4 acc0[8], acc1[8];
#pragma unroll
  for (int t = 0; t < 8; ++t) {
    acc0[t] = f32x4{0.f, 0.f, 0.f, 0.f};
    acc1[t] = f32x4{0.f, 0.f, 0.f, 0.f};
  }
  f32x4 lacc0 = f32x4{0.f, 0.f, 0.f, 0.f};
  f32x4 lacc1 = f32x4{0.f, 0.f, 0.f, 0.f};

  half8 ones;
#pragma unroll
  for (int j = 0; j < 8; ++j) ones[j] = (_Float16)1.0f;

#pragma unroll
  for (int p = 0; p < 4; ++p) gl_lds16(gk[p], &Ks[0][lofs[p]]);
#pragma unroll
  for (int p = 0; p < 4; ++p) gl_lds16(gv[p], &Vs[0][lofs[p]]);

  for (int j = 0; j < NJ; ++j) {
    __syncthreads();
    const int cur = j & 1;
    if (j + 1 < NJ) {
      const size_t ko = (size_t)(j + 1) * 64 * LD;
      const int vo = (j + 1) * 64;
#pragma unroll
      for (int p = 0; p < 4; ++p) gl_lds16(gk[p] + ko, &Ks[cur ^ 1][lofs[p]]);
#pragma unroll
      for (int p = 0; p < 4; ++p) gl_lds16(gv[p] + vo, &Vs[cur ^ 1][lofs[p]]);
    }
    const bool h0 = (j < NJ - 1);
    f32x4 sf0[4], sf1[4];
#pragma unroll
    for (int f = 0; f < 4; ++f) {
      sf0[f] = f32x4{0.f, 0.f, 0.f, 0.f};
      sf1[f] = f32x4{0.f, 0.f, 0.f, 0.f};
    }
#pragma unroll
    for (int f = 0; f < 4; ++f)
#pragma unroll
      for (int ks = 0; ks < 4; ++ks) {
        half8 bk = *reinterpret_cast<const half8*>(&Ks[cur][((f * 4 + ks) * 4 + quad) * 128 + kofs]);
        sf0[f] = __builtin_amdgcn_mfma_f32_16x16x32_f16(aq0[ks], bk, sf0[f], 0, 0, 0);
        sf1[f] = __builtin_amdgcn_mfma_f32_16x16x32_f16(aq1[ks], bk, sf1[f], 0, 0, 0);
      }
    if (j == NJ - 2) {
#pragma unroll
      for (int f = 0; f < 4; ++f) {
        const int key = j * 64 + f * 16 + l16;
#pragma unroll
        for (int r = 0; r < 4; ++r)
          sf0[f][r] = (key <= q0 + quad * 4 + r) ? sf0[f][r] : -1e30f;
      }
    }
    if (j == NJ - 1) {
#pragma unroll
      for (int f = 0; f < 4; ++f) {
        const int key = j * 64 + f * 16 + l16;
#pragma unroll
        for (int r = 0; r < 4; ++r)
          sf1[f][r] = (key <= q0 + 64 + quad * 4 + r) ? sf1[f][r] : -1e30f;
      }
    }
    half8 pa0a, pa0b, pa1a, pa1b;
    if (h0) {
#pragma unroll
      for (int f = 0; f < 4; ++f)
#pragma unroll
        for (int r = 0; r < 4; ++r)
          P[wv][quad * 4 + r][f * 16 + l16] = (_Float16)exp2f(sf0[f][r] - SH);
      pa0a = *reinterpret_cast<const half8*>(&P[wv][l16][quad * 8]);
      pa0b = *reinterpret_cast<const half8*>(&P[wv][l16][32 + quad * 8]);
    }
#pragma unroll
    for (int f = 0; f < 4; ++f)
#pragma unroll
      for (int r = 0; r < 4; ++r)
        P[wv][quad * 4 + r][f * 16 + l16] = (_Float16)exp2f(sf1[f][r] - SH);
    pa1a = *reinterpret_cast<const half8*>(&P[wv][l16][quad * 8]);
    pa1b = *reinterpret_cast<const half8*>(&P[wv][l16][32 + quad * 8]);
#pragma unroll
    for (int t = 0; t < 8; ++t) {
      half8 bv0 = *reinterpret_cast<const half8*>(&Vs[cur][((t * 2 + 0) * 4 + quad) * 128 + kofs]);
      half8 bv1 = *reinterpret_cast<const half8*>(&Vs[cur][((t * 2 + 1) * 4 + quad) * 128 + kofs]);
      if (h0) {
        acc0[t] = __builtin_amdgcn_mfma_f32_16x16x32_f16(pa0a, bv0, acc0[t], 0, 0, 0);
        acc0[t] = __builtin_amdgcn_mfma_f32_16x16x32_f16(pa0b, bv1, acc0[t], 0, 0, 0);
      }
      acc1[t] = __builtin_amdgcn_mfma_f32_16x16x32_f16(pa1a, bv0, acc1[t], 0, 0, 0);
      acc1[t] = __builtin_amdgcn_mfma_f32_16x16x32_f16(pa1b, bv1, acc1[t], 0, 0, 0);
    }
    if (h0) {
      lacc0 = __builtin_amdgcn_mfma_f32_16x16x32_f16(pa0a, ones, lacc0, 0, 0, 0);
      lacc0 = __builtin_amdgcn_mfma_f32_16x16x32_f16(pa0b, ones, lacc0, 0, 0, 0);
    }
    lacc1 = __builtin_amdgcn_mfma_f32_16x16x32_f16(pa1a, ones, lacc1, 0, 0, 0);
    lacc1 = __builtin_amdgcn_mfma_f32_16x16x32_f16(pa1b, ones, lacc1, 0, 0, 0);
  }

  float inv0[4], inv1[4];
#pragma unroll
  for (int r = 0; r < 4; ++r) {
    inv0[r] = 1.0f / lacc0[r];
    inv1[r] = 1.0f / lacc1[r];
  }
#pragma unroll
  for (int t = 0; t < 8; ++t)
#pragma unroll
    for (int r = 0; r < 4; ++r) {
      const int row0 = q0 + quad * 4 + r;
      ctx[(size_t)(b * S + row0) * 2048 + h * 128 + t * 16 + l16] =
          (_Float16)(acc0[t][r] * inv0[r]);
      ctx[(size_t)(b * S + row0 + 64) * 2048 + h * 128 + t * 16 + l16] =
          (_Float16)(acc1[t][r] * inv1[r]);
    }
}

// ---------------- launcher ----------------
extern "C" void kernel_launch(void* const* d_in, const int* in_sizes, int n_in,
                              void* d_out, int out_size, void* d_ws, size_t ws_size,
                              hipStream_t stream) {
  const float* x  = (const float*)d_in[0];
  const float* wq = (const float*)d_in[1];
  const float* bq = (const float*)d_in[2];
  const float* wk = (const float*)d_in[3];
  const float* bk = (const float*)d_in[4];
  const float* wv = (const float*)d_in[5];
  const float* bv = (const float*)d_in[6];
  const float* wo = (const float*)d_in[7];
  const float* bo = (const float*)d_in[8];

  _Float16* W      = (_Float16*)d_ws;
  _Float16* xh     = W;                  // 16 MB (4096,2048)
  _Float16* wqkvh  = xh + 8388608;       // 24 MB (6144,2048) contiguous wq|wk|wv
  _Float16* woh    = wqkvh + 12582912;   // 8 MB  (2048,2048)
  _Float16* qkvlin = woh + 4194304;      // 48 MB (4096,6144)
  _Float16* vT     = xh;                 // reuse: x dead after QKV gemm
  _Float16* ctx    = wqkvh;              // reuse: wqkv dead after QKV gemm

  cast_f32_f16<<<8192, 256, 0, stream>>>(x, xh, 2097152);
  cast_w<<<dim3(4096, 4), 256, 0, stream>>>(wq, wk, wv, wo, wqkvh);

  // fused QKV gemm (+bias +rope +q-scale incl log2e)
  gemm_qkv<<<dim3(24, 16), 512, 0, stream>>>(xh, wqkvh, bq, bk, bv, qkvlin,
                                             4096, 6144, 2048);

  transpose_v<<<dim3(32, 2, 32), 256, 0, stream>>>(qkvlin, vT);
  attn_kernel<<<512, 256, 0, stream>>>(qkvlin, vT, ctx);

  // output gemm: 256 blocks (1/CU)
  gemm_out<<<dim3(16, 16), 512, 0, stream>>>(ctx, woh, bo, (float*)d_out,
                                             4096, 2048, 2048);
}

// Round 9
// 425.905 us; speedup vs baseline: 1.0772x; 1.0772x over previous
//
#include <hip/hip_runtime.h>
#include <math.h>

// MultiHeadAttention: B=2, S=2048, D=2048, H=16, dh=128, causal.
// v12: repairs of v11's two regressions + keep what worked.
//  - attn: v8-exact softmax (__expf(s-5), P stride 80 = 16B-aligned rows;
//    v11's stride-84 broke ds_read_b128 alignment; exp2f was the slow
//    non-intrinsic path). q-scale back to 1/sqrt(128).
//  - gemm_qkv: v5 loop + fused rope, epilogue now ILP-friendly: per j,
//    3 sincos + small r-offset table; each (i,r) coeff is an independent
//    6-op combine (v11's serial 124-step recurrence was the cost).
//  - gemm_out: v10 constexpr/unrolled variant (measured ~6us faster).

typedef _Float16 half8 __attribute__((ext_vector_type(8)));
typedef _Float16 half4v __attribute__((ext_vector_type(4)));
typedef float f32x4 __attribute__((ext_vector_type(4)));

__device__ __forceinline__ void gl_lds16(const void* g, void* l) {
  __builtin_amdgcn_global_load_lds(
      (const __attribute__((address_space(1))) unsigned int*)g,
      (__attribute__((address_space(3))) unsigned int*)l, 16, 0, 0);
}

// ---------------- cast fp32 -> fp16 ----------------
__global__ void cast_f32_f16(const float* __restrict__ src, _Float16* __restrict__ dst, int n4) {
  int i = blockIdx.x * blockDim.x + threadIdx.x;
  if (i >= n4) return;
  float4 v = reinterpret_cast<const float4*>(src)[i];
  half4v o;
  o[0] = (_Float16)v.x; o[1] = (_Float16)v.y; o[2] = (_Float16)v.z; o[3] = (_Float16)v.w;
  reinterpret_cast<half4v*>(dst)[i] = o;
}

__global__ void cast_w(const float* __restrict__ w0, const float* __restrict__ w1,
                       const float* __restrict__ w2, const float* __restrict__ w3,
                       _Float16* __restrict__ wdst) {
  const float* s = blockIdx.y == 0 ? w0 : blockIdx.y == 1 ? w1 : blockIdx.y == 2 ? w2 : w3;
  int i = blockIdx.x * blockDim.x + threadIdx.x;  // < 1048576 float4 groups
  float4 v = reinterpret_cast<const float4*>(s)[i];
  half4v o;
  o[0] = (_Float16)v.x; o[1] = (_Float16)v.y; o[2] = (_Float16)v.z; o[3] = (_Float16)v.w;
  reinterpret_cast<half4v*>(wdst)[(size_t)blockIdx.y * 1048576 + i] = o;
}

// ---------------- QKV GEMM 256x256 (v5 loop) + fused bias/rope/scale ----------------
__global__ __launch_bounds__(512, 2) void gemm_qkv(
    const _Float16* __restrict__ A,   // M x K
    const _Float16* __restrict__ B,   // N x K (wq|wk|wv)
    const float* __restrict__ b0, const float* __restrict__ b1,
    const float* __restrict__ b2,
    _Float16* __restrict__ Cout,      // M x N
    int M, int N, int K) {
  __shared__ _Float16 As[2][16384];  // 64 KB
  __shared__ _Float16 Bs[2][16384];  // 64 KB (sigma-permuted rows)
  const int bm = blockIdx.y * 256, bn = blockIdx.x * 256;
  const int tid = threadIdx.x;
  const int wave = tid >> 6, lane = tid & 63;
  const int quad = lane >> 4, l16 = lane & 15;
  const int wm = (wave >> 2) * 128, wn = (wave & 3) * 64;

  const int srow = tid >> 3;
  const int sx = (tid & 7) ^ (srow & 7);
  const _Float16* Ag = A + (size_t)(bm + srow) * K + sx * 8;
  const _Float16* Bg[4];
#pragma unroll
  for (int c = 0; c < 4; ++c) {
    int r = (((c * 2 + (srow >> 5)) & 3) << 6) + ((c >> 1) << 5) + (srow & 31);
    Bg[c] = B + (size_t)(bn + r) * K + sx * 8;
  }

#define STAGE_A(buf, R, kt) \
  gl_lds16(Ag + (size_t)(R) * K + (kt) * 64, &As[buf][(R) * 64 + tid * 8])
#define STAGE_B(buf, c, kt) \
  gl_lds16(Bg[c] + (kt) * 64, &Bs[buf][(c) * 4096 + tid * 8])

  const int axor = l16 & 7;
  const int sl0 = ((0 + quad) ^ axor) * 8;
  const int sl1 = ((4 + quad) ^ axor) * 8;
  const int aoff = (wm + l16) * 64;
  const int q4 = (wn >> 6) * 32;

#define RD_A(i, kk) \
  (*reinterpret_cast<const half8*>(&As[cur][aoff + (i) * 1024 + ((kk) ? sl1 : sl0)]))
#define RD_B(j, kk) \
  (*reinterpret_cast<const half8*>( \
      &Bs[cur][((((j) >> 1) * 128 + q4 + ((j) & 1) * 16 + l16)) * 64 + ((kk) ? sl1 : sl0)]))

  f32x4 acc[8][4];
#pragma unroll
  for (int i = 0; i < 8; ++i)
#pragma unroll
    for (int j = 0; j < 4; ++j) acc[i][j] = f32x4{0.f, 0.f, 0.f, 0.f};

  half8 a[4][2], b[4][2];
  const int NT = K >> 6;

  STAGE_A(0, 0, 0); STAGE_A(0, 128, 0);
  STAGE_B(0, 0, 0); STAGE_B(0, 1, 0);
  STAGE_B(0, 2, 0); STAGE_B(0, 3, 0);
  STAGE_A(0, 64, 0); STAGE_A(0, 192, 0);
  if (NT > 1) {
    STAGE_A(1, 0, 1); STAGE_A(1, 128, 1);
    STAGE_B(1, 0, 1); STAGE_B(1, 1, 1);
    STAGE_B(1, 2, 1); STAGE_B(1, 3, 1);
    asm volatile("s_waitcnt vmcnt(6)");
  } else {
    asm volatile("s_waitcnt vmcnt(0)");
  }
  __builtin_amdgcn_s_barrier();

  for (int t = 0; t < NT; ++t) {
    const int cur = t & 1, nxt = cur ^ 1;
    const bool pf1 = (t + 1 < NT);
    const bool pf2 = (t + 2 < NT);

    // ---- P1 ----
#pragma unroll
    for (int i = 0; i < 4; ++i) {
      a[i][0] = RD_A(i, 0); a[i][1] = RD_A(i, 1);
    }
#pragma unroll
    for (int j = 0; j < 2; ++j) {
      b[j][0] = RD_B(j, 0); b[j][1] = RD_B(j, 1);
    }
    if (pf1) { STAGE_A(nxt, 64, t + 1); STAGE_A(nxt, 192, t + 1); }
    __builtin_amdgcn_s_barrier();
    __builtin_amdgcn_s_setprio(1);
#pragma unroll
    for (int i = 0; i < 4; ++i)
#pragma unroll
      for (int j = 0; j < 2; ++j) {
        acc[i][j] = __builtin_amdgcn_mfma_f32_16x16x32_f16(a[i][0], b[j][0], acc[i][j], 0, 0, 0);
        acc[i][j] = __builtin_amdgcn_mfma_f32_16x16x32_f16(a[i][1], b[j][1], acc[i][j], 0, 0, 0);
      }
    __builtin_amdgcn_s_setprio(0);
    __builtin_amdgcn_s_barrier();

    // ---- P2 ----
#pragma unroll
    for (int j = 2; j < 4; ++j) {
      b[j][0] = RD_B(j, 0); b[j][1] = RD_B(j, 1);
    }
    if (pf2) { STAGE_A(cur, 0, t + 2); STAGE_A(cur, 128, t + 2); }
    __builtin_amdgcn_s_barrier();
    __builtin_amdgcn_s_setprio(1);
#pragma unroll
    for (int i = 0; i < 4; ++i)
#pragma unroll
      for (int j = 2; j < 4; ++j) {
        acc[i][j] = __builtin_amdgcn_mfma_f32_16x16x32_f16(a[i][0], b[j][0], acc[i][j], 0, 0, 0);
        acc[i][j] = __builtin_amdgcn_mfma_f32_16x16x32_f16(a[i][1], b[j][1], acc[i][j], 0, 0, 0);
      }
    __builtin_amdgcn_s_setprio(0);
    __builtin_amdgcn_s_barrier();

    // ---- P3 ----
#pragma unroll
    for (int i = 0; i < 4; ++i) {
      a[i][0] = RD_A(i + 4, 0); a[i][1] = RD_A(i + 4, 1);
    }
    if (pf2) { STAGE_B(cur, 0, t + 2); STAGE_B(cur, 1, t + 2); }
    __builtin_amdgcn_s_barrier();
    __builtin_amdgcn_s_setprio(1);
#pragma unroll
    for (int i = 0; i < 4; ++i)
#pragma unroll
      for (int j = 0; j < 2; ++j) {
        acc[i + 4][j] = __builtin_amdgcn_mfma_f32_16x16x32_f16(a[i][0], b[j][0], acc[i + 4][j], 0, 0, 0);
        acc[i + 4][j] = __builtin_amdgcn_mfma_f32_16x16x32_f16(a[i][1], b[j][1], acc[i + 4][j], 0, 0, 0);
      }
    __builtin_amdgcn_s_setprio(0);
    __builtin_amdgcn_s_barrier();

    // ---- P4 ----
    if (pf2) { STAGE_B(cur, 2, t + 2); STAGE_B(cur, 3, t + 2); }
    __builtin_amdgcn_s_barrier();
    __builtin_amdgcn_s_setprio(1);
#pragma unroll
    for (int i = 0; i < 4; ++i)
#pragma unroll
      for (int j = 2; j < 4; ++j) {
        acc[i + 4][j] = __builtin_amdgcn_mfma_f32_16x16x32_f16(a[i][0], b[j][0], acc[i + 4][j], 0, 0, 0);
        acc[i + 4][j] = __builtin_amdgcn_mfma_f32_16x16x32_f16(a[i][1], b[j][1], acc[i + 4][j], 0, 0, 0);
      }
    __builtin_amdgcn_s_setprio(0);
    if (pf2)
      asm volatile("s_waitcnt vmcnt(6)");
    else
      asm volatile("s_waitcnt vmcnt(0)");
    __builtin_amdgcn_s_barrier();
  }

  // ---- epilogue: bias + rope (q/k, ILP combined-coefficients) ----
  // region = (bn+wn)>>11 wave-uniform: 0=q, 1=k, 2=v.
  const int region = (bn + wn) >> 11;
  const float qsc = 0.088388347648318447f;  // 1/sqrt(128)
#pragma unroll
  for (int j = 0; j < 4; ++j) {
    const int gc = bn + wn + j * 16 + l16;
    const float* bp = (region == 0) ? b0 : (region == 1 ? b1 : b2);
    const float bz = bp[gc & 2047];
    if (region < 2) {
      const int fi = (gc >> 1) & 63;
      const float fr = exp2f(-0.2076205059304601f * (float)fi);
      // r-offset table (rotations by 0..3 * fr)
      float cr[4], sr[4];
      cr[0] = 1.f; sr[0] = 0.f;
      __sincosf(fr, &sr[1], &cr[1]);
      cr[2] = cr[1] * cr[1] - sr[1] * sr[1];
      sr[2] = 2.f * sr[1] * cr[1];
      cr[3] = cr[2] * cr[1] - sr[2] * sr[1];
      sr[3] = sr[2] * cr[1] + cr[2] * sr[1];
      float c16, s16;
      __sincosf(16.0f * fr, &s16, &c16);
      const float sc = (region == 0) ? qsc : 1.0f;
      const int s0 = (bm + wm + quad * 4) & 2047;
      float cb, sb;
      __sincosf((float)s0 * fr, &sb, &cb);
      cb *= sc; sb *= sc;  // scale folded into base coeffs
      const bool isodd = (gc & 1) != 0;
#pragma unroll
      for (int i = 0; i < 8; ++i) {
#pragma unroll
        for (int r = 0; r < 4; ++r) {
          const int gr = bm + wm + i * 16 + quad * 4 + r;
          float v = acc[i][j][r] + bz;
          const float p = __shfl_xor(v, 1);
          const float C = cb * cr[r] - sb * sr[r];  // independent per (i,r)
          const float S = sb * cr[r] + cb * sr[r];
          float out = isodd ? (v * C + p * S) : (v * C - p * S);
          Cout[(size_t)gr * N + gc] = (_Float16)out;
        }
        // advance base by 16 rows (7 short serial steps total)
        float cn = cb * c16 - sb * s16;
        sb = sb * c16 + cb * s16; cb = cn;
      }
    } else {
#pragma unroll
      for (int i = 0; i < 8; ++i)
#pragma unroll
        for (int r = 0; r < 4; ++r) {
          const int gr = bm + wm + i * 16 + quad * 4 + r;
          Cout[(size_t)gr * N + gc] = (_Float16)(acc[i][j][r] + bz);
        }
    }
  }
#undef STAGE_A
#undef STAGE_B
#undef RD_A
#undef RD_B
}

// ---------------- output GEMM 256x128 constexpr (v10): -> f32 ----------------
__global__ __launch_bounds__(512, 2) void gemm_out(
    const _Float16* __restrict__ A,   // 4096 x 2048
    const _Float16* __restrict__ B,   // 2048 x 2048
    const float* __restrict__ bias,
    float* __restrict__ Cout) {       // 4096 x 2048 f32
  constexpr int K = 2048;
  constexpr int N = 2048;
  constexpr int NT = K >> 6;  // 32 (even)
  __shared__ _Float16 As[2][16384];  // 64 KB
  __shared__ _Float16 Bs[2][8192];   // 32 KB
  const int bm = blockIdx.y * 256, bn = blockIdx.x * 128;
  const int tid = threadIdx.x;
  const int wave = tid >> 6, lane = tid & 63;
  const int quad = lane >> 4, l16 = lane & 15;
  const int wm = (wave >> 2) * 128, wq = wave & 3;

  const int srow = tid >> 3;
  const int sx = (tid & 7) ^ (srow & 7);
  const _Float16* Ag = A + (size_t)(bm + srow) * K + sx * 8;
  const _Float16* Bg[2];
#pragma unroll
  for (int c = 0; c < 2; ++c)
    Bg[c] = B + (size_t)(bn + (srow >> 4) * 32 + c * 16 + (srow & 15)) * K + sx * 8;

#define STAGE_A(buf, R, kt) \
  gl_lds16(Ag + (size_t)(R) * K + (kt) * 64, &As[buf][(R) * 64 + tid * 8])
#define STAGE_B(buf, c, kt) \
  gl_lds16(Bg[c] + (kt) * 64, &Bs[buf][(c) * 4096 + tid * 8])

  const int axor = l16 & 7;
  const int sl0 = ((0 + quad) ^ axor) * 8;
  const int sl1 = ((4 + quad) ^ axor) * 8;
  const int aoff = (wm + l16) * 64;

#define RD_A(i, kk) \
  (*reinterpret_cast<const half8*>(&As[cur][aoff + (i) * 1024 + ((kk) ? sl1 : sl0)]))
#define RD_B(j, kk) \
  (*reinterpret_cast<const half8*>( \
      &Bs[cur][((j) * 64 + wq * 16 + l16) * 64 + ((kk) ? sl1 : sl0)]))

  f32x4 acc[8][2];
#pragma unroll
  for (int i = 0; i < 8; ++i)
#pragma unroll
    for (int j = 0; j < 2; ++j) acc[i][j] = f32x4{0.f, 0.f, 0.f, 0.f};

  half8 a[4][2], b[2][2];

  STAGE_A(0, 0, 0); STAGE_A(0, 128, 0);
  STAGE_B(0, 0, 0); STAGE_B(0, 1, 0);
  STAGE_A(0, 64, 0); STAGE_A(0, 192, 0);
  STAGE_A(1, 0, 1); STAGE_A(1, 128, 1);
  STAGE_B(1, 0, 1); STAGE_B(1, 1, 1);
  STAGE_A(1, 64, 1); STAGE_A(1, 192, 1);
  asm volatile("s_waitcnt vmcnt(6)");
  __builtin_amdgcn_s_barrier();

#define OSTEP_BODY                                                             \
  {                                                                            \
    const bool pf2 = (t + 2 < NT);                                             \
    _Pragma("unroll") for (int i = 0; i < 4; ++i) {                            \
      a[i][0] = RD_A(i, 0); a[i][1] = RD_A(i, 1);                              \
    }                                                                          \
    b[0][0] = RD_B(0, 0); b[0][1] = RD_B(0, 1);                                \
    __builtin_amdgcn_s_barrier();                                              \
    __builtin_amdgcn_s_setprio(1);                                             \
    _Pragma("unroll") for (int i = 0; i < 4; ++i) {                            \
      acc[i][0] = __builtin_amdgcn_mfma_f32_16x16x32_f16(a[i][0], b[0][0], acc[i][0], 0, 0, 0); \
      acc[i][0] = __builtin_amdgcn_mfma_f32_16x16x32_f16(a[i][1], b[0][1], acc[i][0], 0, 0, 0); \
    }                                                                          \
    __builtin_amdgcn_s_setprio(0);                                             \
    __builtin_amdgcn_s_barrier();                                              \
    b[1][0] = RD_B(1, 0); b[1][1] = RD_B(1, 1);                                \
    if (pf2) { STAGE_A(cur, 0, t + 2); STAGE_A(cur, 128, t + 2); }             \
    __builtin_amdgcn_s_barrier();                                              \
    __builtin_amdgcn_s_setprio(1);                                             \
    _Pragma("unroll") for (int i = 0; i < 4; ++i) {                            \
      acc[i][1] = __builtin_amdgcn_mfma_f32_16x16x32_f16(a[i][0], b[1][0], acc[i][1], 0, 0, 0); \
      acc[i][1] = __builtin_amdgcn_mfma_f32_16x16x32_f16(a[i][1], b[1][1], acc[i][1], 0, 0, 0); \
    }                                                                          \
    __builtin_amdgcn_s_setprio(0);                                             \
    __builtin_amdgcn_s_barrier();                                              \
    _Pragma("unroll") for (int i = 0; i < 4; ++i) {                            \
      a[i][0] = RD_A(i + 4, 0); a[i][1] = RD_A(i + 4, 1);                      \
    }                                                                          \
    if (pf2) { STAGE_B(cur, 0, t + 2); STAGE_B(cur, 1, t + 2); }               \
    __builtin_amdgcn_s_barrier();                                              \
    __builtin_amdgcn_s_setprio(1);                                             \
    _Pragma("unroll") for (int i = 0; i < 4; ++i) {                            \
      acc[i + 4][0] = __builtin_amdgcn_mfma_f32_16x16x32_f16(a[i][0], b[0][0], acc[i + 4][0], 0, 0, 0); \
      acc[i + 4][0] = __builtin_amdgcn_mfma_f32_16x16x32_f16(a[i][1], b[0][1], acc[i + 4][0], 0, 0, 0); \
    }                                                                          \
    __builtin_amdgcn_s_setprio(0);                                             \
    __builtin_amdgcn_s_barrier();                                              \
    if (pf2) { STAGE_A(cur, 64, t + 2); STAGE_A(cur, 192, t + 2); }            \
    __builtin_amdgcn_s_barrier();                                              \
    __builtin_amdgcn_s_setprio(1);                                             \
    _Pragma("unroll") for (int i = 0; i < 4; ++i) {                            \
      acc[i + 4][1] = __builtin_amdgcn_mfma_f32_16x16x32_f16(a[i][0], b[1][0], acc[i + 4][1], 0, 0, 0); \
      acc[i + 4][1] = __builtin_amdgcn_mfma_f32_16x16x32_f16(a[i][1], b[1][1], acc[i + 4][1], 0, 0, 0); \
    }                                                                          \
    __builtin_amdgcn_s_setprio(0);                                             \
    if (pf2) asm volatile("s_waitcnt vmcnt(6)");                               \
    else     asm volatile("s_waitcnt vmcnt(0)");                               \
    __builtin_amdgcn_s_barrier();                                              \
  }

  for (int tt = 0; tt < NT; tt += 2) {
    { constexpr int cur = 0; const int t = tt;     OSTEP_BODY }
    { constexpr int cur = 1; const int t = tt + 1; OSTEP_BODY }
  }

#pragma unroll
  for (int j = 0; j < 2; ++j) {
    const int gc = bn + wq * 32 + j * 16 + l16;
    const float bz = bias[gc & 2047];
#pragma unroll
    for (int i = 0; i < 8; ++i) {
#pragma unroll
      for (int r = 0; r < 4; ++r) {
        const int gr = bm + wm + i * 16 + quad * 4 + r;
        Cout[(size_t)gr * N + gc] = acc[i][j][r] + bz;
      }
    }
  }
#undef STAGE_A
#undef STAGE_B
#undef RD_A
#undef RD_B
#undef OSTEP_BODY
}

// ---------------- V transpose: qkv v-cols (stride 6144) -> (B,H,dh,S) ----------------
__global__ __launch_bounds__(256) void transpose_v(const _Float16* __restrict__ qkv,
                                                   _Float16* __restrict__ vt) {
  __shared__ _Float16 t[64][72];
  const int s0 = blockIdx.x * 64;
  const int d0 = blockIdx.y * 64;
  const int bh = blockIdx.z;
  const int b = bh >> 4, h = bh & 15;
  const int tid = threadIdx.x;
#pragma unroll
  for (int p = 0; p < 2; ++p) {
    int chunk = p * 256 + tid;
    int r = chunk >> 3, c8 = (chunk & 7) * 8;
    *reinterpret_cast<half8*>(&t[r][c8]) = *reinterpret_cast<const half8*>(
        &qkv[(size_t)(b * 2048 + s0 + r) * 6144 + 4096 + h * 128 + d0 + c8]);
  }
  __syncthreads();
#pragma unroll
  for (int p = 0; p < 2; ++p) {
    int chunk = p * 256 + tid;
    int dr = chunk >> 3, c8 = (chunk & 7) * 8;
    half8 o;
#pragma unroll
    for (int j = 0; j < 8; ++j) o[j] = t[c8 + j][dr];
    *reinterpret_cast<half8*>(&vt[(size_t)(bh * 128 + d0 + dr) * 2048 + s0 + c8]) = o;
  }
}

// ---------------- Flash attention (causal), dbuf LDS K/V (v8-exact softmax) ----------------
__global__ __launch_bounds__(256, 2) void attn_kernel(
    const _Float16* __restrict__ QKV,  // (4096, 6144): q|k|v
    const _Float16* __restrict__ VT,   // (32, 128, 2048)
    _Float16* __restrict__ ctx) {      // (4096, 2048)
  constexpr int LD = 6144, S = 2048;
  __shared__ _Float16 Ks[2][8192];
  __shared__ _Float16 Vs[2][8192];
  __shared__ _Float16 P[4][16][80];
  const int bid = blockIdx.x;
  const int bh = bid & 31;
  const int idx = (bid >> 5) & 7;
  const int qb = (bid >> 8) ? idx : 15 - idx;  // pairs (bid,bid+256) sum to 15
  const int b = bh >> 4, h = bh & 15;
  const int tid = threadIdx.x;
  const int wv = tid >> 6, lane = tid & 63;
  const int quad = lane >> 4, l16 = lane & 15;
  const int q0 = qb * 128 + wv * 16;   // half0 rows; half1 = q0 + 64
  const int NJ = 2 * qb + 2;           // 64-key tiles

  const _Float16* qp0 = QKV + (size_t)(b * S + q0 + l16) * LD + h * 128;
  half8 aq0[4], aq1[4];
#pragma unroll
  for (int ks = 0; ks < 4; ++ks) {
    aq0[ks] = *reinterpret_cast<const half8*>(qp0 + ks * 32 + quad * 8);
    aq1[ks] = *reinterpret_cast<const half8*>(qp0 + (size_t)64 * LD + ks * 32 + quad * 8);
  }

  const _Float16* gk[4];
  const _Float16* gv[4];
  int lofs[4];
#pragma unroll
  for (int p = 0; p < 4; ++p) {
    int c = p * 256 + tid;
    int cs = c ^ ((c >> 3) & 7);
    int cl16 = cs & 15, cqd = (cs >> 4) & 3;
    int cks = (cs >> 6) & 3, cf = cs >> 8;
    gk[p] = QKV + (size_t)(b * S + cf * 16 + cl16) * LD + 2048 + h * 128 + cks * 32 + cqd * 8;
    int ckv = (cs >> 6) & 1, ct = cs >> 7;
    gv[p] = VT + (size_t)(bh * 128 + ct * 16 + cl16) * S + ckv * 32 + cqd * 8;
    lofs[p] = c * 8;
  }

  const int kofs = (l16 >> 3) * 64 + (((l16 & 7) ^ (quad * 2 + (l16 >> 3)))) * 8;

  f32x4 acc0[8], acc1[8];
#pragma unroll
  for (int t = 0; t < 8; ++t) {
    acc0[t] = f32x4{0.f, 0.f, 0.f, 0.f};
    acc1[t] = f32x4{0.f, 0.f, 0.f, 0.f};
  }
  f32x4 lacc0 = f32x4{0.f, 0.f, 0.f, 0.f};
  f32x4 lacc1 = f32x4{0.f, 0.f, 0.f, 0.f};

  half8 ones;
#pragma unroll
  for (int j = 0; j < 8; ++j) ones[j] = (_Float16)1.0f;

#pragma unroll
  for (int p = 0; p < 4; ++p) gl_lds16(gk[p], &Ks[0][lofs[p]]);
#pragma unroll
  for (int p = 0; p < 4; ++p) gl_lds16(gv[p], &Vs[0][lofs[p]]);

  for (int j = 0; j < NJ; ++j) {
    __syncthreads();
    const int cur = j & 1;
    if (j + 1 < NJ) {
      const size_t ko = (size_t)(j + 1) * 64 * LD;
      const int vo = (j + 1) * 64;
#pragma unroll
      for (int p = 0; p < 4; ++p) gl_lds16(gk[p] + ko, &Ks[cur ^ 1][lofs[p]]);
#pragma unroll
      for (int p = 0; p < 4; ++p) gl_lds16(gv[p] + vo, &Vs[cur ^ 1][lofs[p]]);
    }
    const bool h0 = (j < NJ - 1);
    f32x4 sf0[4], sf1[4];
#pragma unroll
    for (int f = 0; f < 4; ++f) {
      sf0[f] = f32x4{0.f, 0.f, 0.f, 0.f};
      sf1[f] = f32x4{0.f, 0.f, 0.f, 0.f};
    }
#pragma unroll
    for (int f = 0; f < 4; ++f)
#pragma unroll
      for (int ks = 0; ks < 4; ++ks) {
        half8 bk = *reinterpret_cast<const half8*>(&Ks[cur][((f * 4 + ks) * 4 + quad) * 128 + kofs]);
        sf0[f] = __builtin_amdgcn_mfma_f32_16x16x32_f16(aq0[ks], bk, sf0[f], 0, 0, 0);
        sf1[f] = __builtin_amdgcn_mfma_f32_16x16x32_f16(aq1[ks], bk, sf1[f], 0, 0, 0);
      }
    if (j == NJ - 2) {
#pragma unroll
      for (int f = 0; f < 4; ++f) {
        const int key = j * 64 + f * 16 + l16;
#pragma unroll
        for (int r = 0; r < 4; ++r)
          sf0[f][r] = (key <= q0 + quad * 4 + r) ? sf0[f][r] : -1e30f;
      }
    }
    if (j == NJ - 1) {
#pragma unroll
      for (int f = 0; f < 4; ++f) {
        const int key = j * 64 + f * 16 + l16;
#pragma unroll
        for (int r = 0; r < 4; ++r)
          sf1[f][r] = (key <= q0 + 64 + quad * 4 + r) ? sf1[f][r] : -1e30f;
      }
    }
    half8 pa0a, pa0b, pa1a, pa1b;
    if (h0) {
#pragma unroll
      for (int f = 0; f < 4; ++f)
#pragma unroll
        for (int r = 0; r < 4; ++r)
          P[wv][quad * 4 + r][f * 16 + l16] = (_Float16)__expf(sf0[f][r] - 5.0f);
      pa0a = *reinterpret_cast<const half8*>(&P[wv][l16][quad * 8]);
      pa0b = *reinterpret_cast<const half8*>(&P[wv][l16][32 + quad * 8]);
    }
#pragma unroll
    for (int f = 0; f < 4; ++f)
#pragma unroll
      for (int r = 0; r < 4; ++r)
        P[wv][quad * 4 + r][f * 16 + l16] = (_Float16)__expf(sf1[f][r] - 5.0f);
    pa1a = *reinterpret_cast<const half8*>(&P[wv][l16][quad * 8]);
    pa1b = *reinterpret_cast<const half8*>(&P[wv][l16][32 + quad * 8]);
#pragma unroll
    for (int t = 0; t < 8; ++t) {
      half8 bv0 = *reinterpret_cast<const half8*>(&Vs[cur][((t * 2 + 0) * 4 + quad) * 128 + kofs]);
      half8 bv1 = *reinterpret_cast<const half8*>(&Vs[cur][((t * 2 + 1) * 4 + quad) * 128 + kofs]);
      if (h0) {
        acc0[t] = __builtin_amdgcn_mfma_f32_16x16x32_f16(pa0a, bv0, acc0[t], 0, 0, 0);
        acc0[t] = __builtin_amdgcn_mfma_f32_16x16x32_f16(pa0b, bv1, acc0[t], 0, 0, 0);
      }
      acc1[t] = __builtin_amdgcn_mfma_f32_16x16x32_f16(pa1a, bv0, acc1[t], 0, 0, 0);
      acc1[t] = __builtin_amdgcn_mfma_f32_16x16x32_f16(pa1b, bv1, acc1[t], 0, 0, 0);
    }
    if (h0) {
      lacc0 = __builtin_amdgcn_mfma_f32_16x16x32_f16(pa0a, ones, lacc0, 0, 0, 0);
      lacc0 = __builtin_amdgcn_mfma_f32_16x16x32_f16(pa0b, ones, lacc0, 0, 0, 0);
    }
    lacc1 = __builtin_amdgcn_mfma_f32_16x16x32_f16(pa1a, ones, lacc1, 0, 0, 0);
    lacc1 = __builtin_amdgcn_mfma_f32_16x16x32_f16(pa1b, ones, lacc1, 0, 0, 0);
  }

  float inv0[4], inv1[4];
#pragma unroll
  for (int r = 0; r < 4; ++r) {
    inv0[r] = 1.0f / lacc0[r];
    inv1[r] = 1.0f / lacc1[r];
  }
#pragma unroll
  for (int t = 0; t < 8; ++t)
#pragma unroll
    for (int r = 0; r < 4; ++r) {
      const int row0 = q0 + quad * 4 + r;
      ctx[(size_t)(b * S + row0) * 2048 + h * 128 + t * 16 + l16] =
          (_Float16)(acc0[t][r] * inv0[r]);
      ctx[(size_t)(b * S + row0 + 64) * 2048 + h * 128 + t * 16 + l16] =
          (_Float16)(acc1[t][r] * inv1[r]);
    }
}

// ---------------- launcher ----------------
extern "C" void kernel_launch(void* const* d_in, const int* in_sizes, int n_in,
                              void* d_out, int out_size, void* d_ws, size_t ws_size,
                              hipStream_t stream) {
  const float* x  = (const float*)d_in[0];
  const float* wq = (const float*)d_in[1];
  const float* bq = (const float*)d_in[2];
  const float* wk = (const float*)d_in[3];
  const float* bk = (const float*)d_in[4];
  const float* wv = (const float*)d_in[5];
  const float* bv = (const float*)d_in[6];
  const float* wo = (const float*)d_in[7];
  const float* bo = (const float*)d_in[8];

  _Float16* W      = (_Float16*)d_ws;
  _Float16* xh     = W;                  // 16 MB (4096,2048)
  _Float16* wqkvh  = xh + 8388608;       // 24 MB (6144,2048) contiguous wq|wk|wv
  _Float16* woh    = wqkvh + 12582912;   // 8 MB  (2048,2048)
  _Float16* qkvlin = woh + 4194304;      // 48 MB (4096,6144)
  _Float16* vT     = xh;                 // reuse: x dead after QKV gemm
  _Float16* ctx    = wqkvh;              // reuse: wqkv dead after QKV gemm

  cast_f32_f16<<<8192, 256, 0, stream>>>(x, xh, 2097152);
  cast_w<<<dim3(4096, 4), 256, 0, stream>>>(wq, wk, wv, wo, wqkvh);

  // fused QKV gemm (+bias +rope +q-scale)
  gemm_qkv<<<dim3(24, 16), 512, 0, stream>>>(xh, wqkvh, bq, bk, bv, qkvlin,
                                             4096, 6144, 2048);

  transpose_v<<<dim3(32, 2, 32), 256, 0, stream>>>(qkvlin, vT);
  attn_kernel<<<512, 256, 0, stream>>>(qkvlin, vT, ctx);

  // output gemm: 256 blocks (1/CU)
  gemm_out<<<dim3(16, 16), 512, 0, stream>>>(ctx, woh, bo, (float*)d_out);
}